// Round 2
// baseline (1089.892 us; speedup 1.0000x reference)
//
#include <hip/hip_runtime.h>
#include <math.h>

// AGNNet: h = relu(x@W1+b1); h = AGNN(h, beta=1); h = AGNN(h, beta3); out = log_softmax(h@W4+b4)
// Strategy:
//  - CSR built per launch (graph identical for both convs): count -> scan(3 kernels) -> scatter.
//  - GEMM: 256-thread blocks, BM=128 rows, BK=64 LDS-staged x tile (stride 68 -> conflict-free
//    ds_read_b128 since thread rows are rg+32m, bank=4*rg), 4 rows x 2 cols per thread so W1
//    is amortized from L1. HBM floor = reading x (400 MB) ~ 63us.
//  - Conv: quarter-wave (16 lanes) per dst node; SINGLE pass over edges: coalesced 64B gather
//    of xn[src], shfl_xor dot-reduce, e=exp(beta*dot), acc += e*nrm[src]*xn[src], s += e;
//    out = acc/s. No ebuf, no float atomics, no segment_max (alpha in [-beta,beta], softmax
//    shift-invariant; eps 1e-16 negligible since self-loop guarantees s >= exp(-|beta|)).

#define NN 50000
#define EE 1600000
#define ETOT 1650000   // EE + NN self loops
#define FIN 2000
#define NH 16
#define NC 20

#define BM 128
#define BK 64
#define LDSK 68

__global__ __launch_bounds__(256) void k_zero(int* __restrict__ cnt) {
  int i = blockIdx.x * 256 + threadIdx.x;
  if (i < NN) cnt[i] = 0;
}

__global__ __launch_bounds__(256) void k_count(const int* __restrict__ ei, int* __restrict__ cnt) {
  int e = blockIdx.x * 256 + threadIdx.x;
  if (e >= ETOT) return;
  int dst = (e < EE) ? ei[EE + e] : (e - EE);
  atomicAdd(&cnt[dst], 1);
}

__global__ __launch_bounds__(1024) void k_scan1(const int* __restrict__ cnt, int* __restrict__ rowst,
                                                int* __restrict__ btot) {
  __shared__ int sh[1024];
  int t = threadIdx.x;
  int i = blockIdx.x * 1024 + t;
  int v = (i < NN) ? cnt[i] : 0;
  sh[t] = v;
  __syncthreads();
  for (int off = 1; off < 1024; off <<= 1) {
    int u = (t >= off) ? sh[t - off] : 0;
    __syncthreads();
    sh[t] += u;
    __syncthreads();
  }
  if (i < NN) rowst[i] = sh[t] - v;          // exclusive within block
  if (t == 1023) btot[blockIdx.x] = sh[1023];
}

__global__ void k_scan2(int* __restrict__ btot, int nb) {
  if (threadIdx.x == 0 && blockIdx.x == 0) {
    int run = 0;
    for (int b = 0; b < nb; ++b) { int v = btot[b]; btot[b] = run; run += v; }
  }
}

__global__ __launch_bounds__(1024) void k_scan3(const int* __restrict__ btot, int* __restrict__ rowst,
                                                int* __restrict__ cursor) {
  int t = threadIdx.x;
  int i = blockIdx.x * 1024 + t;
  if (i < NN) {
    int v = rowst[i] + btot[blockIdx.x];
    rowst[i] = v;
    cursor[i] = v;
  }
  if (i == NN) rowst[NN] = ETOT;
}

__global__ __launch_bounds__(256) void k_scatter(const int* __restrict__ ei, int* __restrict__ cursor,
                                                 int* __restrict__ srcs) {
  int e = blockIdx.x * 256 + threadIdx.x;
  if (e >= ETOT) return;
  int src, dst;
  if (e < EE) { src = ei[e]; dst = ei[EE + e]; }
  else        { src = e - EE; dst = e - EE; }
  int pos = atomicAdd(&cursor[dst], 1);
  srcs[pos] = src;
}

// ---------------- GEMM: h = relu(x @ W1 + b1) ----------------
__global__ __launch_bounds__(256) void k_gemm_relu(const float* __restrict__ x,
                                                   const float* __restrict__ W1,
                                                   const float* __restrict__ b1,
                                                   float* __restrict__ h) {
  __shared__ float xs[BM * LDSK];
  const int tid = threadIdx.x;
  const int rowBase = blockIdx.x * BM;
  const int rg = tid >> 3;   // 0..31 ; within a wave rg in 0..7 -> distinct LDS banks
  const int cg = tid & 7;    // 0..7  ; cols c0 = 2*cg
  const int c0 = cg * 2;
  const float2* wp = reinterpret_cast<const float2*>(W1);

  float acc[4][2] = {{0.f,0.f},{0.f,0.f},{0.f,0.f},{0.f,0.f}};

  for (int kt = 0; kt < FIN; kt += BK) {
    // stage x tile [BM][BK] (zero-padded at edges), coalesced float4
#pragma unroll
    for (int rnd = 0; rnd < 8; ++rnd) {
      int idx = rnd * 256 + tid;
      int row = idx >> 4;
      int col = (idx & 15) * 4;
      int gr = rowBase + row;
      int gk = kt + col;
      float4 v = make_float4(0.f, 0.f, 0.f, 0.f);
      if (gr < NN && gk < FIN)
        v = *reinterpret_cast<const float4*>(x + (size_t)gr * FIN + gk);
      *reinterpret_cast<float4*>(&xs[row * LDSK + col]) = v;
    }
    __syncthreads();

#pragma unroll
    for (int kk = 0; kk < 16; ++kk) {
      int k = kt + kk * 4;
      float2 w[4];
#pragma unroll
      for (int j = 0; j < 4; ++j) {
        int kc = k + j;                      // wave-uniform; clamp (x is zero-padded there)
        kc = (kc < FIN) ? kc : (FIN - 1);
        w[j] = wp[kc * 8 + cg];
      }
#pragma unroll
      for (int m = 0; m < 4; ++m) {
        float4 xv = *reinterpret_cast<const float4*>(&xs[(rg + 32 * m) * LDSK + kk * 4]);
        acc[m][0] = fmaf(xv.x, w[0].x, acc[m][0]);
        acc[m][0] = fmaf(xv.y, w[1].x, acc[m][0]);
        acc[m][0] = fmaf(xv.z, w[2].x, acc[m][0]);
        acc[m][0] = fmaf(xv.w, w[3].x, acc[m][0]);
        acc[m][1] = fmaf(xv.x, w[0].y, acc[m][1]);
        acc[m][1] = fmaf(xv.y, w[1].y, acc[m][1]);
        acc[m][1] = fmaf(xv.z, w[2].y, acc[m][1]);
        acc[m][1] = fmaf(xv.w, w[3].y, acc[m][1]);
      }
    }
    __syncthreads();
  }

  float2 bb = *reinterpret_cast<const float2*>(&b1[c0]);
#pragma unroll
  for (int m = 0; m < 4; ++m) {
    int gr = rowBase + rg + 32 * m;
    if (gr < NN) {
      float2 o;
      o.x = fmaxf(acc[m][0] + bb.x, 0.f);
      o.y = fmaxf(acc[m][1] + bb.y, 0.f);
      *reinterpret_cast<float2*>(&h[(size_t)gr * NH + c0]) = o;
    }
  }
}

// ---------------- row L2-normalize: xn = in/(||in||+1e-12), nrm = ||in||+1e-12 ----------------
__global__ __launch_bounds__(256) void k_norm(const float* __restrict__ in, float* __restrict__ outn,
                                              float* __restrict__ nrm) {
  int r = blockIdx.x * 256 + threadIdx.x;
  if (r >= NN) return;
  const float4* p = reinterpret_cast<const float4*>(in + (size_t)r * NH);
  float4 a = p[0], b = p[1], c = p[2], d = p[3];
  float ss = a.x*a.x + a.y*a.y + a.z*a.z + a.w*a.w
           + b.x*b.x + b.y*b.y + b.z*b.z + b.w*b.w
           + c.x*c.x + c.y*c.y + c.z*c.z + c.w*c.w
           + d.x*d.x + d.y*d.y + d.z*d.z + d.w*d.w;
  float nr = sqrtf(ss) + 1e-12f;
  float inv = 1.0f / nr;
  nrm[r] = nr;
  float4* q = reinterpret_cast<float4*>(outn + (size_t)r * NH);
  q[0] = make_float4(a.x*inv, a.y*inv, a.z*inv, a.w*inv);
  q[1] = make_float4(b.x*inv, b.y*inv, b.z*inv, b.w*inv);
  q[2] = make_float4(c.x*inv, c.y*inv, c.z*inv, c.w*inv);
  q[3] = make_float4(d.x*inv, d.y*inv, d.z*inv, d.w*inv);
}

// ---------------- AGNN conv: quarter-wave per dst, single pass ----------------
__global__ __launch_bounds__(256) void k_conv(const float* __restrict__ xn,   // normalized feats
                                              const float* __restrict__ nrm,  // row norms
                                              const int* __restrict__ rowst,
                                              const int* __restrict__ srcs,
                                              float* __restrict__ outv,
                                              const float* __restrict__ beta_ptr) {
  int tid = threadIdx.x;
  int c = tid & 15;
  int q = tid >> 4;
  int d = blockIdx.x * 16 + q;
  if (d >= NN) return;
  float beta = beta_ptr ? beta_ptr[0] : 1.0f;
  int beg = rowst[d];
  int end = rowst[d + 1];
  float xd = xn[(size_t)d * NH + c];
  float s = 0.f;
  float acc = 0.f;
  for (int i = beg; i < end; ++i) {
    int sv = srcs[i];
    float xs = xn[(size_t)sv * NH + c];
    float nr = nrm[sv];                 // same addr across 16 lanes -> broadcast
    float p = xs * xd;
    p += __shfl_xor(p, 1);
    p += __shfl_xor(p, 2);
    p += __shfl_xor(p, 4);
    p += __shfl_xor(p, 8);
    float e = __expf(beta * p);         // |beta*p| <= |beta|: no overflow, max-sub skipped
    s += e;
    acc = fmaf(e * nr, xs, acc);        // e * raw_x_src[c]
  }
  outv[(size_t)d * NH + c] = acc / (s + 1e-16f);
}

// ---------------- linear4 + log_softmax ----------------
__global__ __launch_bounds__(256) void k_final(const float* __restrict__ h2,
                                               const float* __restrict__ W4,
                                               const float* __restrict__ b4,
                                               float* __restrict__ out) {
  int r = blockIdx.x * 256 + threadIdx.x;
  if (r >= NN) return;
  float hr[NH];
  const float4* p = reinterpret_cast<const float4*>(h2 + (size_t)r * NH);
#pragma unroll
  for (int j = 0; j < 4; ++j) {
    float4 v = p[j];
    hr[j*4+0] = v.x; hr[j*4+1] = v.y; hr[j*4+2] = v.z; hr[j*4+3] = v.w;
  }
  float lg[NC];
#pragma unroll
  for (int c = 0; c < NC; ++c) {
    float a = b4[c];
#pragma unroll
    for (int k = 0; k < NH; ++k) a = fmaf(hr[k], W4[k * NC + c], a);
    lg[c] = a;
  }
  float mx = lg[0];
#pragma unroll
  for (int c = 1; c < NC; ++c) mx = fmaxf(mx, lg[c]);
  float ssum = 0.f;
#pragma unroll
  for (int c = 0; c < NC; ++c) ssum += __expf(lg[c] - mx);
  float lse = mx + __logf(ssum);
#pragma unroll
  for (int c = 0; c < NC; ++c) out[(size_t)r * NC + c] = lg[c] - lse;
}

extern "C" void kernel_launch(void* const* d_in, const int* in_sizes, int n_in,
                              void* d_out, int out_size, void* d_ws, size_t ws_size,
                              hipStream_t stream) {
  const float* x     = (const float*)d_in[0];
  const int*   ei    = (const int*)d_in[1];
  const float* W1    = (const float*)d_in[2];
  const float* b1    = (const float*)d_in[3];
  const float* W4    = (const float*)d_in[4];
  const float* b4    = (const float*)d_in[5];
  const float* beta3 = (const float*)d_in[6];
  float* out = (float*)d_out;

  // workspace layout (~17 MB)
  float* buf0 = (float*)d_ws;          // h, later reused as g2
  float* buf1 = buf0 + (size_t)NN*NH;  // xn (both convs)
  float* buf2 = buf1 + (size_t)NN*NH;  // g1
  float* nrm  = buf2 + (size_t)NN*NH;  // NN row norms
  int* srcs   = (int*)(nrm + NN);      // ETOT ints
  int* cnt    = srcs + ETOT;           // NN
  int* rowst  = cnt + NN;              // NN+1
  int* cursor = rowst + NN + 1;        // NN
  int* btot   = cursor + NN;           // 64

  const int nb = (NN + 1023) / 1024;   // 49

  // build CSR (shared by both convs)
  k_zero<<<(NN + 255) / 256, 256, 0, stream>>>(cnt);
  k_count<<<(ETOT + 255) / 256, 256, 0, stream>>>(ei, cnt);
  k_scan1<<<nb, 1024, 0, stream>>>(cnt, rowst, btot);
  k_scan2<<<1, 64, 0, stream>>>(btot, nb);
  k_scan3<<<nb, 1024, 0, stream>>>(btot, rowst, cursor);
  k_scatter<<<(ETOT + 255) / 256, 256, 0, stream>>>(ei, cursor, srcs);

  // pipeline
  k_gemm_relu<<<(NN + BM - 1) / BM, 256, 0, stream>>>(x, W1, b1, buf0);
  k_norm<<<(NN + 255) / 256, 256, 0, stream>>>(buf0, buf1, nrm);
  k_conv<<<NN / 16, 256, 0, stream>>>(buf1, nrm, rowst, srcs, buf2, nullptr);
  k_norm<<<(NN + 255) / 256, 256, 0, stream>>>(buf2, buf1, nrm);
  k_conv<<<NN / 16, 256, 0, stream>>>(buf1, nrm, rowst, srcs, buf0, beta3);
  k_final<<<(NN + 255) / 256, 256, 0, stream>>>(buf0, W4, b4, out);
}